// Round 4
// baseline (214.141 us; speedup 1.0000x reference)
//
#include <hip/hip_runtime.h>
#include <cstdint>
#include <cstddef>

#define EPSF 1e-6f

typedef __attribute__((ext_vector_type(4))) float f32x4;
typedef __attribute__((ext_vector_type(8))) short s16x8;
typedef union { s16x8 v; unsigned u[4]; } s16x8u;

// hi/lo dual-bf16 pack via v_cvt_pk_bf16_f32 (1 inst packs 2 floats).
// Residual is computed against the EXACT decode (bf16<<16), so any rounding
// mode in cvt_pk is absorbed by the lo term.
static __device__ __forceinline__ void pack2(float a, float b, unsigned& H, unsigned& L) {
    unsigned h, l;
    asm("v_cvt_pk_bf16_f32 %0, %1, %2" : "=v"(h) : "v"(a), "v"(b));
    float ra = a - __uint_as_float(h << 16);
    float rb = b - __uint_as_float(h & 0xffff0000u);
    asm("v_cvt_pk_bf16_f32 %0, %1, %2" : "=v"(l) : "v"(ra), "v"(rb));
    H = h; L = l;
}
static __device__ __forceinline__ unsigned packH(float a, float b) {
    unsigned h;
    asm("v_cvt_pk_bf16_f32 %0, %1, %2" : "=v"(h) : "v"(a), "v"(b));
    return h;
}

// ws layout (4B units):
//   [0    ..  575]  w1n branch0: [c][9] normalized taps (fp32)
//   [576  .. 1151]  w1n branch1
//   [1152 .. 5247]  w2H branch0 [128][32] u32 c-pair hi
//   [5248 .. 9343]  w2L branch0 [128][32] u32 c-pair lo
//   [9344 ..13439]  w2H branch1
//   [13440..17535]  w2L branch1

__global__ __launch_bounds__(256) void prep(const float* __restrict__ w1,
                                            const float* __restrict__ w2,
                                            float* __restrict__ ws) {
    __shared__ float s1row[64];
    __shared__ float red[4];
    __shared__ float rs8[8];
    const int t = threadIdx.x;
    const int lane = t & 63;
    const int wv = t >> 6;
    const int gid = blockIdx.x * 256 + t;

    // t2 = sum over all 8192 w2^2
    float s = 0.f;
    #pragma unroll
    for (int i = 0; i < 32; ++i) { float v = w2[t + 256 * i]; s += v * v; }
    #pragma unroll
    for (int d = 32; d > 0; d >>= 1) s += __shfl_xor(s, d);
    if (lane == 0) red[wv] = s;

    // w1 row sums (64 rows x 9 taps)
    if (t < 64) {
        float rs = 0.f;
        #pragma unroll
        for (int k = 0; k < 9; ++k) { float v = w1[t * 9 + k]; rs += v * v; }
        s1row[t] = rs;
    }

    // per-row w2 sums for the 8 rows this block packs (blocks 0..15 only)
    if (blockIdx.x < 16) {
        const int r8 = t >> 5;            // 0..7
        const int e = t & 31;
        const int row = blockIdx.x * 8 + r8;
        float v0 = w2[row * 64 + e];
        float v1 = w2[row * 64 + 32 + e];
        float rr = v0 * v0 + v1 * v1;
        #pragma unroll
        for (int d = 16; d > 0; d >>= 1) rr += __shfl_down(rr, d);
        if (e == 0) rs8[r8] = rr;
    }
    __syncthreads();

    const float t2 = red[0] + red[1] + red[2] + red[3];
    float a = s1row[lane];
    #pragma unroll
    for (int d = 32; d > 0; d >>= 1) a += __shfl_xor(a, d);
    const float t1 = a;

    unsigned* wsu = (unsigned*)ws;
    if (gid < 4096) {
        const int row = gid >> 5;
        const int cp = gid & 31;
        float v0 = w2[row * 64 + 2 * cp];
        float v1 = w2[row * 64 + 2 * cp + 1];
        float q0 = v0 * v0, q1 = v1 * v1;
        const float rs = rs8[t >> 5];
        unsigned H, L;
        pack2(q0 / t2, q1 / t2, H, L);
        wsu[1152 + row * 32 + cp] = H;
        wsu[5248 + row * 32 + cp] = L;
        pack2(q0 / rs, q1 / rs, H, L);
        wsu[9344 + row * 32 + cp] = H;
        wsu[13440 + row * 32 + cp] = L;
    } else if (gid < 4672) {
        const int i = gid - 4096;
        const int c = i / 9;
        const int k = i - c * 9;
        float v = w1[i];
        float q = v * v;
        ws[c * 9 + k] = q / t1;
        ws[576 + c * 9 + k] = q / s1row[c];
    }
}

// grid: (32, 2, 62)  block: 512 (8 waves). ONE output row per block.
//   - LDS halved to 16.9 KB (rot buffers hold 64 px, not 128)
//   - per-thread state halved: va[3] input rows, acc[4] (each wave owns a
//     16-oc tile: oc = w*16, no mt dimension)
//   - NO __shfl_down: the 2 extra border pixels come from a float2 tail load
//     (removes ds_bpermute dependency mid-FMA-chain + its bank conflicts)
//   - channel b x-loads issued AFTER channel a's compute (caps live regs so
//     the allocator lands <=64 naturally; (512,4) is only a 128-reg safety
//     cap -- NOT a forced occupancy like rounds 2/3 which caused spills)
// Branch 0 (rot): single bf16 term (outputs O(1e-4), abs err ~2e-7).
// Branch 1 (abs/exp): 3-term hi/lo split (AhBh + AhBl + AlBh).
__global__ __launch_bounds__(512, 4) void conv_fused(const float* __restrict__ x,
                                                     const float* __restrict__ ws,
                                                     float* __restrict__ out) {
    const int b = blockIdx.x;
    const int branch = blockIdx.y;
    const int h = blockIdx.z;              // output row 0..61
    const int t = threadIdx.x;
    const int lane = t & 63;
    const int w = __builtin_amdgcn_readfirstlane(t >> 6);
    const int lm = lane & 15;
    const int q = lane >> 4;
    const bool dual = (branch != 0);

    __shared__ unsigned rotH[64 * 33];
    __shared__ unsigned rotL[64 * 33];

    const float* __restrict__ w1n = ws + branch * 576;
    const unsigned* __restrict__ wsu = (const unsigned*)ws;
    const unsigned* __restrict__ w2H = wsu + 1152 + branch * 8192;
    const unsigned* __restrict__ w2L = w2H + 4096;
    const float* __restrict__ xb = x + (size_t)(b * 2 + branch) * (64 * 4096);

    const int cpair = w * 4 + q;
    const int c0 = 2 * cpair;
    const int oc0 = w * 16;                // wave's 16-oc tile

    const float* xp = xb + c0 * 4096 + h * 64;
    const int x0 = 4 * lm;
    const int xe = (lm < 15) ? 4 * lm + 4 : 60;   // tail: clamped for lm=15
                                                   // (feeds only px>=62, never stored)

    float pa[4], pb[4];

    // ---- channel a: loads + A-fragments (L2-hot) issued together ----
    float4 va[3]; float2 ea[3];
    #pragma unroll
    for (int r = 0; r < 3; ++r) va[r] = *(const float4*)(xp + r * 64 + x0);
    #pragma unroll
    for (int r = 0; r < 3; ++r) ea[r] = *(const float2*)(xp + r * 64 + xe);

    s16x8u aH[2], aL[2];
    #pragma unroll
    for (int kk = 0; kk < 2; ++kk) {
        const int off = (oc0 + lm) * 32 + kk * 16 + q * 4;
        #pragma unroll
        for (int j = 0; j < 4; ++j) aH[kk].u[j] = w2H[off + j];
    }
    if (dual) {
        #pragma unroll
        for (int kk = 0; kk < 2; ++kk) {
            const int off = (oc0 + lm) * 32 + kk * 16 + q * 4;
            #pragma unroll
            for (int j = 0; j < 4; ++j) aL[kk].u[j] = w2L[off + j];
        }
    }

    const float* wc0 = w1n + c0 * 9;
    if (dual) {
        #pragma unroll
        for (int r = 0; r < 3; ++r) {
            va[r].x = __logf(va[r].x + EPSF); va[r].y = __logf(va[r].y + EPSF);
            va[r].z = __logf(va[r].z + EPSF); va[r].w = __logf(va[r].w + EPSF);
            ea[r].x = __logf(ea[r].x + EPSF); ea[r].y = __logf(ea[r].y + EPSF);
        }
    }
    #pragma unroll
    for (int rr = 0; rr < 3; ++rr) {
        const float4 u = va[rr];
        const float e0 = ea[rr].x, e1 = ea[rr].y;
        const float t0 = wc0[rr * 3], t1_ = wc0[rr * 3 + 1], t2_ = wc0[rr * 3 + 2];
        if (rr == 0) {
            pa[0] = u.x * t0 + u.y * t1_ + u.z * t2_;
            pa[1] = u.y * t0 + u.z * t1_ + u.w * t2_;
            pa[2] = u.z * t0 + u.w * t1_ + e0 * t2_;
            pa[3] = u.w * t0 + e0 * t1_ + e1 * t2_;
        } else {
            pa[0] += u.x * t0 + u.y * t1_ + u.z * t2_;
            pa[1] += u.y * t0 + u.z * t1_ + u.w * t2_;
            pa[2] += u.z * t0 + u.w * t1_ + e0 * t2_;
            pa[3] += u.w * t0 + e0 * t1_ + e1 * t2_;
        }
    }

    // ---- channel b: loads issued after channel a's compute (reg cap) ----
    {
        float4 vb[3]; float2 eb[3];
        #pragma unroll
        for (int r = 0; r < 3; ++r) vb[r] = *(const float4*)(xp + 4096 + r * 64 + x0);
        #pragma unroll
        for (int r = 0; r < 3; ++r) eb[r] = *(const float2*)(xp + 4096 + r * 64 + xe);

        const float* wc1 = wc0 + 9;
        if (dual) {
            #pragma unroll
            for (int r = 0; r < 3; ++r) {
                vb[r].x = __logf(vb[r].x + EPSF); vb[r].y = __logf(vb[r].y + EPSF);
                vb[r].z = __logf(vb[r].z + EPSF); vb[r].w = __logf(vb[r].w + EPSF);
                eb[r].x = __logf(eb[r].x + EPSF); eb[r].y = __logf(eb[r].y + EPSF);
            }
        }
        #pragma unroll
        for (int rr = 0; rr < 3; ++rr) {
            const float4 u = vb[rr];
            const float e0 = eb[rr].x, e1 = eb[rr].y;
            const float t0 = wc1[rr * 3], t1_ = wc1[rr * 3 + 1], t2_ = wc1[rr * 3 + 2];
            if (rr == 0) {
                pb[0] = u.x * t0 + u.y * t1_ + u.z * t2_;
                pb[1] = u.y * t0 + u.z * t1_ + u.w * t2_;
                pb[2] = u.z * t0 + u.w * t1_ + e0 * t2_;
                pb[3] = u.w * t0 + e0 * t1_ + e1 * t2_;
            } else {
                pb[0] += u.x * t0 + u.y * t1_ + u.z * t2_;
                pb[1] += u.y * t0 + u.z * t1_ + u.w * t2_;
                pb[2] += u.z * t0 + u.w * t1_ + e0 * t2_;
                pb[3] += u.w * t0 + e0 * t1_ + e1 * t2_;
            }
        }
    }

    // ---- pack + LDS write ----
    #pragma unroll
    for (int i = 0; i < 4; ++i) {
        const int px = 4 * lm + i;
        if (dual) {
            unsigned H, L;
            pack2(pa[i], pb[i], H, L);
            rotH[px * 33 + cpair] = H;
            rotL[px * 33 + cpair] = L;
        } else {
            rotH[px * 33 + cpair] = packH(pa[i], pb[i]);
        }
    }
    __syncthreads();

    // ---- phase 2: MFMA, wave tile = 16 oc x 64 px ----
    f32x4 acc[4];
    #pragma unroll
    for (int nt = 0; nt < 4; ++nt) acc[nt] = (f32x4){0.f, 0.f, 0.f, 0.f};

    __builtin_amdgcn_s_setprio(1);
    if (dual) {
        #pragma unroll
        for (int nt = 0; nt < 4; ++nt) {
            #pragma unroll
            for (int kk = 0; kk < 2; ++kk) {
                const int idx = (nt * 16 + lm) * 33 + kk * 16 + q * 4;
                s16x8u bH, bL;
                #pragma unroll
                for (int j = 0; j < 4; ++j) bH.u[j] = rotH[idx + j];
                #pragma unroll
                for (int j = 0; j < 4; ++j) bL.u[j] = rotL[idx + j];
                acc[nt] = __builtin_amdgcn_mfma_f32_16x16x32_bf16(aH[kk].v, bH.v, acc[nt], 0, 0, 0);
                acc[nt] = __builtin_amdgcn_mfma_f32_16x16x32_bf16(aH[kk].v, bL.v, acc[nt], 0, 0, 0);
                acc[nt] = __builtin_amdgcn_mfma_f32_16x16x32_bf16(aL[kk].v, bH.v, acc[nt], 0, 0, 0);
            }
        }
    } else {
        #pragma unroll
        for (int nt = 0; nt < 4; ++nt) {
            #pragma unroll
            for (int kk = 0; kk < 2; ++kk) {
                const int idx = (nt * 16 + lm) * 33 + kk * 16 + q * 4;
                s16x8u bH;
                #pragma unroll
                for (int j = 0; j < 4; ++j) bH.u[j] = rotH[idx + j];
                acc[nt] = __builtin_amdgcn_mfma_f32_16x16x32_bf16(aH[kk].v, bH.v, acc[nt], 0, 0, 0);
            }
        }
    }
    __builtin_amdgcn_s_setprio(0);

    // ---- epilogue: D row = oc (q*4+r), col = nt*16+lm ----
    const int ocr = oc0 + q * 4;
    #pragma unroll
    for (int nt = 0; nt < 4; ++nt) {
        const int col = nt * 16 + lm;
        if (col < 62) {
            const size_t base =
                ((size_t)((b * 2 + branch) * 128 + ocr)) * 3844 +
                (size_t)h * 62 + col;
            #pragma unroll
            for (int r = 0; r < 4; ++r) {
                float v = acc[nt][r];
                if (dual) v = __expf(v);
                out[base + (size_t)r * 3844] = v;
            }
        }
    }
}

extern "C" void kernel_launch(void* const* d_in, const int* in_sizes, int n_in,
                              void* d_out, int out_size, void* d_ws, size_t ws_size,
                              hipStream_t stream) {
    const float* x  = (const float*)d_in[0];
    const float* w1 = (const float*)d_in[1];
    const float* w2 = (const float*)d_in[2];
    float* out = (float*)d_out;
    float* ws  = (float*)d_ws;

    prep<<<19, 256, 0, stream>>>(w1, w2, ws);

    dim3 grid(32, 2, 62);
    conv_fused<<<grid, 512, 0, stream>>>(x, ws, out);
}

// Round 6
// 203.138 us; speedup vs baseline: 1.0542x; 1.0542x over previous
//
#include <hip/hip_runtime.h>
#include <cstdint>
#include <cstddef>

#define EPSF 1e-6f

typedef __attribute__((ext_vector_type(4))) float f32x4;
typedef __attribute__((ext_vector_type(8))) short s16x8;
typedef union { s16x8 v; unsigned u[4]; } s16x8u;

// hi/lo dual-bf16 pack via v_cvt_pk_bf16_f32 (1 inst packs 2 floats).
// Residual is computed against the EXACT decode (bf16<<16), so any rounding
// mode in cvt_pk is absorbed by the lo term.
static __device__ __forceinline__ void pack2(float a, float b, unsigned& H, unsigned& L) {
    unsigned h, l;
    asm("v_cvt_pk_bf16_f32 %0, %1, %2" : "=v"(h) : "v"(a), "v"(b));
    float ra = a - __uint_as_float(h << 16);
    float rb = b - __uint_as_float(h & 0xffff0000u);
    asm("v_cvt_pk_bf16_f32 %0, %1, %2" : "=v"(l) : "v"(ra), "v"(rb));
    H = h; L = l;
}
static __device__ __forceinline__ unsigned packH(float a, float b) {
    unsigned h;
    asm("v_cvt_pk_bf16_f32 %0, %1, %2" : "=v"(h) : "v"(a), "v"(b));
    return h;
}

// ws layout (4B units):
//   [0    ..  575]  w1n branch0: [c][9] normalized taps (fp32)
//   [576  .. 1151]  w1n branch1
//   [1152 .. 5247]  w2H branch0 [128][32] u32 c-pair hi
//   [5248 .. 9343]  w2L branch0 [128][32] u32 c-pair lo
//   [9344 ..13439]  w2H branch1
//   [13440..17535]  w2L branch1

__global__ __launch_bounds__(256) void prep(const float* __restrict__ w1,
                                            const float* __restrict__ w2,
                                            float* __restrict__ ws) {
    __shared__ float s1row[64];
    __shared__ float red[4];
    __shared__ float rs8[8];
    const int t = threadIdx.x;
    const int lane = t & 63;
    const int wv = t >> 6;
    const int gid = blockIdx.x * 256 + t;

    // t2 = sum over all 8192 w2^2
    float s = 0.f;
    #pragma unroll
    for (int i = 0; i < 32; ++i) { float v = w2[t + 256 * i]; s += v * v; }
    #pragma unroll
    for (int d = 32; d > 0; d >>= 1) s += __shfl_xor(s, d);
    if (lane == 0) red[wv] = s;

    // w1 row sums (64 rows x 9 taps)
    if (t < 64) {
        float rs = 0.f;
        #pragma unroll
        for (int k = 0; k < 9; ++k) { float v = w1[t * 9 + k]; rs += v * v; }
        s1row[t] = rs;
    }

    // per-row w2 sums for the 8 rows this block packs (blocks 0..15 only)
    if (blockIdx.x < 16) {
        const int r8 = t >> 5;            // 0..7
        const int e = t & 31;
        const int row = blockIdx.x * 8 + r8;
        float v0 = w2[row * 64 + e];
        float v1 = w2[row * 64 + 32 + e];
        float rr = v0 * v0 + v1 * v1;
        #pragma unroll
        for (int d = 16; d > 0; d >>= 1) rr += __shfl_down(rr, d);
        if (e == 0) rs8[r8] = rr;
    }
    __syncthreads();

    const float t2 = red[0] + red[1] + red[2] + red[3];
    float a = s1row[lane];
    #pragma unroll
    for (int d = 32; d > 0; d >>= 1) a += __shfl_xor(a, d);
    const float t1 = a;

    unsigned* wsu = (unsigned*)ws;
    if (gid < 4096) {
        const int row = gid >> 5;
        const int cp = gid & 31;
        float v0 = w2[row * 64 + 2 * cp];
        float v1 = w2[row * 64 + 2 * cp + 1];
        float q0 = v0 * v0, q1 = v1 * v1;
        const float rs = rs8[t >> 5];
        unsigned H, L;
        pack2(q0 / t2, q1 / t2, H, L);
        wsu[1152 + row * 32 + cp] = H;
        wsu[5248 + row * 32 + cp] = L;
        pack2(q0 / rs, q1 / rs, H, L);
        wsu[9344 + row * 32 + cp] = H;
        wsu[13440 + row * 32 + cp] = L;
    } else if (gid < 4672) {
        const int i = gid - 4096;
        const int c = i / 9;
        const int k = i - c * 9;
        float v = w1[i];
        float q = v * v;
        ws[c * 9 + k] = q / t1;
        ws[576 + c * 9 + k] = q / s1row[c];
    }
}

// grid: (32, 2, 31)  block: 512 (8 waves). TWO output rows per block (r1's
// amortization: 4 input rows -> 2 output rows) + r4's register discipline:
//   - channels sequenced (ch-a loads+compute, then ch-b) -> peak live ~56
//   - NO __shfl_down: border pixels via float2 tail loads (redundant reads are
//     LLC-hits; removes the ds_bpermute dependency chain mid-FMA)
//   - A-fragments loaded after the pack (pa/pb dead), latency under barrier
//   - phase 2: wave tile = 16 oc x 128 px, nt split in 2 groups of 4 so only
//     acc[4] (16 regs) live; epilogue interleaved per group
//   - plain __launch_bounds__(512): natural allocation (r2/r3's forced caps
//     caused spills); target 3-4 blocks/CU (LDS 33KB caps at 4)
// Branch 0 (rot): single bf16 term (outputs O(1e-4), abs err ~2e-7).
// Branch 1 (abs/exp): 3-term hi/lo split (AhBh + AhBl + AlBh).
__global__ __launch_bounds__(512) void conv_fused(const float* __restrict__ x,
                                                  const float* __restrict__ ws,
                                                  float* __restrict__ out) {
    const int b = blockIdx.x;
    const int branch = blockIdx.y;
    const int hg = blockIdx.z;
    const int h0 = hg * 2;
    const int t = threadIdx.x;
    const int lane = t & 63;
    const int w = __builtin_amdgcn_readfirstlane(t >> 6);
    const int lm = lane & 15;
    const int q = lane >> 4;
    const bool dual = (branch != 0);

    __shared__ unsigned rotH[128 * 33];
    __shared__ unsigned rotL[128 * 33];

    const float* __restrict__ w1n = ws + branch * 576;
    const unsigned* __restrict__ wsu = (const unsigned*)ws;
    const unsigned* __restrict__ w2H = wsu + 1152 + branch * 8192;
    const unsigned* __restrict__ w2L = w2H + 4096;
    const float* __restrict__ xb = x + (size_t)(b * 2 + branch) * (64 * 4096);

    const int cpair = w * 4 + q;
    const int c0 = 2 * cpair;
    const int oc0 = w * 16;                    // wave's 16-oc tile

    const float* xp = xb + c0 * 4096 + h0 * 64;
    const int x0 = 4 * lm;
    const int xe = (lm < 15) ? x0 + 4 : 60;    // tail; lm=15 clamped (feeds only
                                               // px>=62, never stored)
    float pa[2][4], pb[2][4];

    // ---- channel a: 4 rows (float4 + float2 tail) ----
    {
        float4 va[4]; float2 ea[4];
        #pragma unroll
        for (int r = 0; r < 4; ++r) va[r] = *(const float4*)(xp + r * 64 + x0);
        #pragma unroll
        for (int r = 0; r < 4; ++r) ea[r] = *(const float2*)(xp + r * 64 + xe);

        const float* wc0 = w1n + c0 * 9;
        if (dual) {
            #pragma unroll
            for (int r = 0; r < 4; ++r) {
                va[r].x = __logf(va[r].x + EPSF); va[r].y = __logf(va[r].y + EPSF);
                va[r].z = __logf(va[r].z + EPSF); va[r].w = __logf(va[r].w + EPSF);
                ea[r].x = __logf(ea[r].x + EPSF); ea[r].y = __logf(ea[r].y + EPSF);
            }
        }
        #pragma unroll
        for (int row = 0; row < 2; ++row) {
            #pragma unroll
            for (int rr = 0; rr < 3; ++rr) {
                const float4 u = va[row + rr];
                const float e0 = ea[row + rr].x, e1 = ea[row + rr].y;
                const float t0 = wc0[rr * 3], t1_ = wc0[rr * 3 + 1], t2_ = wc0[rr * 3 + 2];
                if (rr == 0) {
                    pa[row][0] = u.x * t0 + u.y * t1_ + u.z * t2_;
                    pa[row][1] = u.y * t0 + u.z * t1_ + u.w * t2_;
                    pa[row][2] = u.z * t0 + u.w * t1_ + e0 * t2_;
                    pa[row][3] = u.w * t0 + e0 * t1_ + e1 * t2_;
                } else {
                    pa[row][0] += u.x * t0 + u.y * t1_ + u.z * t2_;
                    pa[row][1] += u.y * t0 + u.z * t1_ + u.w * t2_;
                    pa[row][2] += u.z * t0 + u.w * t1_ + e0 * t2_;
                    pa[row][3] += u.w * t0 + e0 * t1_ + e1 * t2_;
                }
            }
        }
    }

    // ---- channel b: loads issued after channel a's compute (reg cap) ----
    {
        float4 vb[4]; float2 eb[4];
        #pragma unroll
        for (int r = 0; r < 4; ++r) vb[r] = *(const float4*)(xp + 4096 + r * 64 + x0);
        #pragma unroll
        for (int r = 0; r < 4; ++r) eb[r] = *(const float2*)(xp + 4096 + r * 64 + xe);

        const float* wc1 = w1n + c0 * 9 + 9;
        if (dual) {
            #pragma unroll
            for (int r = 0; r < 4; ++r) {
                vb[r].x = __logf(vb[r].x + EPSF); vb[r].y = __logf(vb[r].y + EPSF);
                vb[r].z = __logf(vb[r].z + EPSF); vb[r].w = __logf(vb[r].w + EPSF);
                eb[r].x = __logf(eb[r].x + EPSF); eb[r].y = __logf(eb[r].y + EPSF);
            }
        }
        #pragma unroll
        for (int row = 0; row < 2; ++row) {
            #pragma unroll
            for (int rr = 0; rr < 3; ++rr) {
                const float4 u = vb[row + rr];
                const float e0 = eb[row + rr].x, e1 = eb[row + rr].y;
                const float t0 = wc1[rr * 3], t1_ = wc1[rr * 3 + 1], t2_ = wc1[rr * 3 + 2];
                if (rr == 0) {
                    pb[row][0] = u.x * t0 + u.y * t1_ + u.z * t2_;
                    pb[row][1] = u.y * t0 + u.z * t1_ + u.w * t2_;
                    pb[row][2] = u.z * t0 + u.w * t1_ + e0 * t2_;
                    pb[row][3] = u.w * t0 + e0 * t1_ + e1 * t2_;
                } else {
                    pb[row][0] += u.x * t0 + u.y * t1_ + u.z * t2_;
                    pb[row][1] += u.y * t0 + u.z * t1_ + u.w * t2_;
                    pb[row][2] += u.z * t0 + u.w * t1_ + e0 * t2_;
                    pb[row][3] += u.w * t0 + e0 * t1_ + e1 * t2_;
                }
            }
        }
    }

    // ---- pack + LDS write ----
    #pragma unroll
    for (int row = 0; row < 2; ++row) {
        #pragma unroll
        for (int i = 0; i < 4; ++i) {
            const int pxl = row * 64 + 4 * lm + i;
            if (dual) {
                unsigned H, L;
                pack2(pa[row][i], pb[row][i], H, L);
                rotH[pxl * 33 + cpair] = H;
                rotL[pxl * 33 + cpair] = L;
            } else {
                rotH[pxl * 33 + cpair] = packH(pa[row][i], pb[row][i]);
            }
        }
    }

    // ---- A fragments: pa/pb dead here; latency hides under the barrier ----
    s16x8u aH[2], aL[2];
    #pragma unroll
    for (int kk = 0; kk < 2; ++kk) {
        const int off = (oc0 + lm) * 32 + kk * 16 + q * 4;
        #pragma unroll
        for (int j = 0; j < 4; ++j) aH[kk].u[j] = w2H[off + j];
    }
    if (dual) {
        #pragma unroll
        for (int kk = 0; kk < 2; ++kk) {
            const int off = (oc0 + lm) * 32 + kk * 16 + q * 4;
            #pragma unroll
            for (int j = 0; j < 4; ++j) aL[kk].u[j] = w2L[off + j];
        }
    }
    __syncthreads();

    // ---- phase 2: wave tile = 16 oc x 128 px, two nt-groups of 4 ----
    const int ocr = oc0 + q * 4;
    #pragma unroll
    for (int g = 0; g < 2; ++g) {
        f32x4 acc[4];
        #pragma unroll
        for (int ntl = 0; ntl < 4; ++ntl) acc[ntl] = (f32x4){0.f, 0.f, 0.f, 0.f};

        __builtin_amdgcn_s_setprio(1);
        if (dual) {
            #pragma unroll
            for (int ntl = 0; ntl < 4; ++ntl) {
                #pragma unroll
                for (int kk = 0; kk < 2; ++kk) {
                    const int idx = ((g * 4 + ntl) * 16 + lm) * 33 + kk * 16 + q * 4;
                    s16x8u bH, bL;
                    #pragma unroll
                    for (int j = 0; j < 4; ++j) bH.u[j] = rotH[idx + j];
                    #pragma unroll
                    for (int j = 0; j < 4; ++j) bL.u[j] = rotL[idx + j];
                    acc[ntl] = __builtin_amdgcn_mfma_f32_16x16x32_bf16(aH[kk].v, bH.v, acc[ntl], 0, 0, 0);
                    acc[ntl] = __builtin_amdgcn_mfma_f32_16x16x32_bf16(aH[kk].v, bL.v, acc[ntl], 0, 0, 0);
                    acc[ntl] = __builtin_amdgcn_mfma_f32_16x16x32_bf16(aL[kk].v, bH.v, acc[ntl], 0, 0, 0);
                }
            }
        } else {
            #pragma unroll
            for (int ntl = 0; ntl < 4; ++ntl) {
                #pragma unroll
                for (int kk = 0; kk < 2; ++kk) {
                    const int idx = ((g * 4 + ntl) * 16 + lm) * 33 + kk * 16 + q * 4;
                    s16x8u bH;
                    #pragma unroll
                    for (int j = 0; j < 4; ++j) bH.u[j] = rotH[idx + j];
                    acc[ntl] = __builtin_amdgcn_mfma_f32_16x16x32_bf16(aH[kk].v, bH.v, acc[ntl], 0, 0, 0);
                }
            }
        }
        __builtin_amdgcn_s_setprio(0);

        // ---- epilogue group g: out row h0+g, col = ntl*16+lm ----
        #pragma unroll
        for (int ntl = 0; ntl < 4; ++ntl) {
            const int col = ntl * 16 + lm;
            if (col < 62) {
                const size_t base =
                    ((size_t)((b * 2 + branch) * 128 + ocr)) * 3844 +
                    (size_t)(h0 + g) * 62 + col;
                #pragma unroll
                for (int r = 0; r < 4; ++r) {
                    float v = acc[ntl][r];
                    if (dual) v = __expf(v);
                    out[base + (size_t)r * 3844] = v;
                }
            }
        }
    }
}

extern "C" void kernel_launch(void* const* d_in, const int* in_sizes, int n_in,
                              void* d_out, int out_size, void* d_ws, size_t ws_size,
                              hipStream_t stream) {
    const float* x  = (const float*)d_in[0];
    const float* w1 = (const float*)d_in[1];
    const float* w2 = (const float*)d_in[2];
    float* out = (float*)d_out;
    float* ws  = (float*)d_ws;

    prep<<<19, 256, 0, stream>>>(w1, w2, ws);

    dim3 grid(32, 2, 31);
    conv_fused<<<grid, 512, 0, stream>>>(x, ws, out);
}